// Round 3
// baseline (258.621 us; speedup 1.0000x reference)
//
#include <hip/hip_runtime.h>
#include <hip/hip_bf16.h>

// GQA causal attention fwd: B=1, H=16, HKV=4, S=2048, D=128, fp32 in/out.
// Round 3: swapped QK^T (S^T, per-lane-scalar softmax), packed b64 P path,
// T13 defer-rescale, single-buffer LDS (40KB) + T14 reg-staged prefetch.

#define NH    16
#define NHKV  4
#define SEQ   2048
#define DIM   128
#define QBLK  64
#define KVBLK 64
#define NT    (SEQ / KVBLK)   // 32 kv tiles

typedef __attribute__((ext_vector_type(8))) short bf16x8_t;
typedef __attribute__((ext_vector_type(4))) float f32x4_t;

__device__ inline ushort f2bf(float f) {
    uint x = __float_as_uint(f);
    uint r = (x + 0x7fffu + ((x >> 16) & 1u)) >> 16;
    return (ushort)r;
}

// ---- prep: K -> bf16 swizzled [kvh][tile][row*256 + d*2 ^ swz] images,
//            V -> bf16 transposed swizzled [kvh][tile][d*128 + kv*2 ^ swz]
extern "C" __global__ __launch_bounds__(256)
void prep_kv(const float* __restrict__ K, const float* __restrict__ V,
             ushort* __restrict__ Kpre, ushort* __restrict__ Vpre)
{
    int gid = blockIdx.x * 256 + threadIdx.x;
    if (blockIdx.x < 1024) {
        int kvh = gid >> 16; int rem = gid & 65535;
        int s = rem >> 5; int dq = (rem & 31) << 2;
        float4 f = *(const float4*)(K + ((size_t)(kvh * SEQ + s)) * DIM + dq);
        uint lo = (uint)f2bf(f.x) | ((uint)f2bf(f.y) << 16);
        uint hi = (uint)f2bf(f.z) | ((uint)f2bf(f.w) << 16);
        int tile = s >> 6, row = s & 63;
        uint byte = ((uint)(row * 256 + dq * 2)) ^ ((uint)(row & 7) << 4);
        *(uint2*)((char*)Kpre + (((size_t)(kvh * NT + tile)) << 14) + byte) =
            make_uint2(lo, hi);
    } else {
        int g2 = gid - 1024 * 256;
        int kvh = g2 >> 16; int rem = g2 & 65535;
        int d = rem & 127; int t2 = rem >> 7;
        int tile = t2 >> 4; int kv = (t2 & 15) << 2;
        const float* b = V + ((size_t)(kvh * SEQ + tile * 64 + kv)) * DIM + d;
        uint lo = (uint)f2bf(b[0])       | ((uint)f2bf(b[DIM]) << 16);
        uint hi = (uint)f2bf(b[2 * DIM]) | ((uint)f2bf(b[3 * DIM]) << 16);
        uint byte = ((uint)(d * 128 + kv * 2)) ^ ((uint)(d & 7) << 4);
        *(uint2*)((char*)Vpre + (((size_t)(kvh * NT + tile)) << 14) + byte) =
            make_uint2(lo, hi);
    }
}

extern "C" __global__ __launch_bounds__(256, 3)
void attn_fwd(const float* __restrict__ Q, const ushort* __restrict__ Kpre,
              const ushort* __restrict__ Vpre, float* __restrict__ O)
{
    const int h   = blockIdx.y;
    const int kvh = h >> 2;                         // gqa_group_size = 4
    const int qt  = (SEQ / QBLK - 1) - blockIdx.x;  // longest blocks first
    const int q0  = qt * QBLK;
    const int tid  = threadIdx.x;
    const int w    = tid >> 6;
    const int lane = tid & 63;
    const int g    = lane >> 4;   // 0..3
    const int r    = lane & 15;   // 0..15

    // single-buffered swizzled bf16 tile images (staged from pre-images)
    __shared__ ushort Ksh[KVBLK * DIM];    // 16 KB
    __shared__ ushort Vtsh[DIM * KVBLK];   // 16 KB
    __shared__ ushort Psh[4 * 16 * 64];    // 8 KB (2 KB per wave)

    const float qscale = 0.08838834764831845f * 1.4426950408889634f; // 1/sqrt(D)*log2e
    const uint swz = ((uint)(r & 7)) << 4;

    // ---- Q fragments (B-frag: col = q = lane&15, k = g*8 + i), pre-scaled ----
    bf16x8_t qf[4];
    {
        const int qrow = q0 + w * 16 + r;
        const float* qp = Q + ((size_t)h * SEQ + qrow) * DIM + g * 8;
#pragma unroll
        for (int kb = 0; kb < 4; ++kb) {
            float4 f0 = *(const float4*)(qp + kb * 32);
            float4 f1 = *(const float4*)(qp + kb * 32 + 4);
            bf16x8_t a;
            a[0] = (short)f2bf(f0.x * qscale); a[1] = (short)f2bf(f0.y * qscale);
            a[2] = (short)f2bf(f0.z * qscale); a[3] = (short)f2bf(f0.w * qscale);
            a[4] = (short)f2bf(f1.x * qscale); a[5] = (short)f2bf(f1.y * qscale);
            a[6] = (short)f2bf(f1.z * qscale); a[7] = (short)f2bf(f1.w * qscale);
            qf[kb] = a;
        }
    }

    f32x4_t o_acc[8];
#pragma unroll
    for (int i = 0; i < 8; ++i) { f32x4_t z = {0.f, 0.f, 0.f, 0.f}; o_acc[i] = z; }
    float m_r = -1e30f, l_r = 0.f;   // per-lane scalar softmax state (q = r)

    const size_t kvbase = (size_t)kvh * NT;
    const int nt = qt + 1;

    // ---- T14 reg staging: 4x uint4 K + 4x uint4 V per thread (32 KB/tile) ----
    uint4 sk[4], sv[4];
    {
        const char* kg = (const char*)Kpre + (kvbase << 14);
        const char* vg = (const char*)Vpre + (kvbase << 14);
#pragma unroll
        for (int c = 0; c < 4; ++c) {
            sk[c] = *(const uint4*)(kg + tid * 16 + c * 4096);
            sv[c] = *(const uint4*)(vg + tid * 16 + c * 4096);
        }
    }

    char* pbase = (char*)Psh + w * 2048;

    for (int t = 0; t < nt; ++t) {
        __syncthreads();               // all waves done reading previous tile
#pragma unroll
        for (int c = 0; c < 4; ++c) {  // regs -> LDS (vmcnt wait by compiler)
            *(uint4*)((char*)Ksh + tid * 16 + c * 4096) = sk[c];
            *(uint4*)((char*)Vtsh + tid * 16 + c * 4096) = sv[c];
        }
        if (t + 1 < nt) {              // issue next-tile loads; fly under compute
            const char* kg = (const char*)Kpre + ((kvbase + t + 1) << 14);
            const char* vg = (const char*)Vpre + ((kvbase + t + 1) << 14);
#pragma unroll
            for (int c = 0; c < 4; ++c) {
                sk[c] = *(const uint4*)(kg + tid * 16 + c * 4096);
                sv[c] = *(const uint4*)(vg + tid * 16 + c * 4096);
            }
        }
        __syncthreads();               // LDS tile ready

        const bool diag = (t == nt - 1);

        // ---- swapped QK^T: S^T[kv][q], lane holds q=r, kv = m*16+g*4+reg ----
        f32x4_t sacc[4];
#pragma unroll
        for (int m = 0; m < 4; ++m) { f32x4_t z = {0.f, 0.f, 0.f, 0.f}; sacc[m] = z; }
        __builtin_amdgcn_s_setprio(1);
#pragma unroll
        for (int m = 0; m < 4; ++m) {
            if (diag && m > w) {       // fully-masked kv sub-tile: skip MFMAs
#pragma unroll
                for (int j2 = 0; j2 < 4; ++j2) sacc[m][j2] = -1e30f;
            } else {
                const int krow = m * 16 + r;   // A-frag row = kv
#pragma unroll
                for (int kb = 0; kb < 4; ++kb) {
                    uint byte = ((uint)(krow * 256 + (kb * 32 + g * 8) * 2)) ^ swz;
                    bf16x8_t kf = *(bf16x8_t*)((char*)Ksh + byte);
                    sacc[m] = __builtin_amdgcn_mfma_f32_16x16x32_bf16(kf, qf[kb], sacc[m], 0, 0, 0);
                }
                if (diag && m == w) {  // partial mask on the diagonal sub-tile
#pragma unroll
                    for (int j2 = 0; j2 < 4; ++j2)
                        if (g * 4 + j2 > r) sacc[m][j2] = -1e30f;
                }
            }
        }
        __builtin_amdgcn_s_setprio(0);

        // ---- row max: 15 local max + 2 shfl (over g groups) ----
        float pmax = sacc[0][0];
#pragma unroll
        for (int m = 0; m < 4; ++m)
#pragma unroll
            for (int j2 = 0; j2 < 4; ++j2) pmax = fmaxf(pmax, sacc[m][j2]);
        pmax = fmaxf(pmax, __shfl_xor(pmax, 16, 64));
        pmax = fmaxf(pmax, __shfl_xor(pmax, 32, 64));

        // ---- T13 defer-rescale (exp2 domain, THR = 8) ----
        if (!__all(pmax - m_r <= 8.f)) {
            float mnew = fmaxf(m_r, pmax);
            float alpha = __builtin_exp2f(m_r - mnew);
            m_r = mnew;
            l_r *= alpha;
#pragma unroll
            for (int pr = 0; pr < 4; ++pr) {
                float ao = __shfl(alpha, g * 20 + pr, 64);  // lane with r == g*4+pr
#pragma unroll
                for (int nd = 0; nd < 8; ++nd) o_acc[nd][pr] *= ao;
            }
        }

        // ---- P = exp2(S - m), pack pairs, sum ----
        float psum = 0.f;
        uint Wd[4][2];
#pragma unroll
        for (int m = 0; m < 4; ++m) {
            float p0 = __builtin_exp2f(sacc[m][0] - m_r);
            float p1 = __builtin_exp2f(sacc[m][1] - m_r);
            float p2 = __builtin_exp2f(sacc[m][2] - m_r);
            float p3 = __builtin_exp2f(sacc[m][3] - m_r);
            psum += (p0 + p1) + (p2 + p3);
            Wd[m][0] = (uint)f2bf(p0) | ((uint)f2bf(p1) << 16);
            Wd[m][1] = (uint)f2bf(p2) | ((uint)f2bf(p3) << 16);
        }
        psum += __shfl_xor(psum, 16, 64);
        psum += __shfl_xor(psum, 32, 64);
        l_r += psum;

        // ---- P -> LDS (4x b64), rows = q = r, cols = kv = 16m+4g.. ----
#pragma unroll
        for (int m = 0; m < 4; ++m) {
            uint byte = ((uint)(r * 128 + m * 32 + g * 8)) ^ swz;
            *(uint2*)(pbase + byte) = make_uint2(Wd[m][0], Wd[m][1]);
        }
        asm volatile("s_waitcnt lgkmcnt(0)" ::: "memory");

        // ---- PV: O[q][d] += P[q][kv] V[kv][d] ----
        __builtin_amdgcn_s_setprio(1);
#pragma unroll
        for (int kb = 0; kb < 2; ++kb) {
            uint pbyte = ((uint)(r * 128 + kb * 64 + g * 16)) ^ swz;
            bf16x8_t pa = *(bf16x8_t*)(pbase + pbyte);
#pragma unroll
            for (int nd = 0; nd < 8; ++nd) {
                int d = nd * 16 + r;
                uint vbyte = ((uint)(d * 128 + (kb * 32 + g * 8) * 2)) ^ swz;
                bf16x8_t vb = *(bf16x8_t*)((char*)Vtsh + vbyte);
                o_acc[nd] = __builtin_amdgcn_mfma_f32_16x16x32_bf16(pa, vb, o_acc[nd], 0, 0, 0);
            }
        }
        __builtin_amdgcn_s_setprio(0);
    }

    // ---- epilogue: O = acc / l (l redistributed from q=r lanes) ----
#pragma unroll
    for (int pr = 0; pr < 4; ++pr) {
        float lq = __shfl(l_r, g * 20 + pr, 64);
        float inv = 1.0f / lq;
        int qrow = q0 + w * 16 + g * 4 + pr;
        float* op = O + ((size_t)h * SEQ + qrow) * DIM;
#pragma unroll
        for (int nd = 0; nd < 8; ++nd)
            op[nd * 16 + r] = o_acc[nd][pr] * inv;
    }
}

extern "C" void kernel_launch(void* const* d_in, const int* in_sizes, int n_in,
                              void* d_out, int out_size, void* d_ws, size_t ws_size,
                              hipStream_t stream) {
    const float* Q = (const float*)d_in[0];
    const float* K = (const float*)d_in[1];
    const float* V = (const float*)d_in[2];
    float* O = (float*)d_out;
    ushort* Kpre = (ushort*)d_ws;                          // 2 MB
    ushort* Vpre = (ushort*)((char*)d_ws + (2u << 20));    // 2 MB
    prep_kv<<<2048, 256, 0, stream>>>(K, V, Kpre, Vpre);
    dim3 grid(SEQ / QBLK, NH);
    attn_fwd<<<grid, 256, 0, stream>>>(Q, Kpre, Vpre, O);
}

// Round 6
// 140.876 us; speedup vs baseline: 1.8358x; 1.8358x over previous
//
#include <hip/hip_runtime.h>
#include <hip/hip_bf16.h>

// GQA causal attention fwd: B=1, H=16, HKV=4, S=2048, D=128, fp32 in/out.
// Round 5 (resubmit; r4/r5 benches were broker timeouts): r2's double-buffered
// global_load_lds staging (no reg spill) + r3's swapped-QK^T scalar softmax,
// T13 defer-rescale, packed P path, diagonal MFMA skip. Work-balanced
// bid->(qt,h) pairing (qt=p with 31-p).

#define NH    16
#define NHKV  4
#define SEQ   2048
#define DIM   128
#define QBLK  64
#define KVBLK 64
#define NT    (SEQ / KVBLK)   // 32 kv tiles

typedef __attribute__((ext_vector_type(8))) short bf16x8_t;
typedef __attribute__((ext_vector_type(4))) float f32x4_t;

__device__ inline ushort f2bf(float f) {
    uint x = __float_as_uint(f);
    uint r = (x + 0x7fffu + ((x >> 16) & 1u)) >> 16;
    return (ushort)r;
}

#define GLOAD_LDS16(gsrc, ldst) \
    __builtin_amdgcn_global_load_lds( \
        (const __attribute__((address_space(1))) void*)(gsrc), \
        (__attribute__((address_space(3))) void*)(ldst), 16, 0, 0)

// ---- prep: K -> bf16 swizzled [kvh][tile][row*256 + d*2 ^ swz] images,
//            V -> bf16 transposed swizzled [kvh][tile][d*128 + kv*2 ^ swz]
extern "C" __global__ __launch_bounds__(256)
void prep_kv(const float* __restrict__ K, const float* __restrict__ V,
             ushort* __restrict__ Kpre, ushort* __restrict__ Vpre)
{
    int gid = blockIdx.x * 256 + threadIdx.x;
    if (blockIdx.x < 1024) {
        int kvh = gid >> 16; int rem = gid & 65535;
        int s = rem >> 5; int dq = (rem & 31) << 2;
        float4 f = *(const float4*)(K + ((size_t)(kvh * SEQ + s)) * DIM + dq);
        uint lo = (uint)f2bf(f.x) | ((uint)f2bf(f.y) << 16);
        uint hi = (uint)f2bf(f.z) | ((uint)f2bf(f.w) << 16);
        int tile = s >> 6, row = s & 63;
        uint byte = ((uint)(row * 256 + dq * 2)) ^ ((uint)(row & 7) << 4);
        *(uint2*)((char*)Kpre + (((size_t)(kvh * NT + tile)) << 14) + byte) =
            make_uint2(lo, hi);
    } else {
        int g2 = gid - 1024 * 256;
        int kvh = g2 >> 16; int rem = g2 & 65535;
        int d = rem & 127; int t2 = rem >> 7;
        int tile = t2 >> 4; int kv = (t2 & 15) << 2;
        const float* b = V + ((size_t)(kvh * SEQ + tile * 64 + kv)) * DIM + d;
        uint lo = (uint)f2bf(b[0])       | ((uint)f2bf(b[DIM]) << 16);
        uint hi = (uint)f2bf(b[2 * DIM]) | ((uint)f2bf(b[3 * DIM]) << 16);
        uint byte = ((uint)(d * 128 + kv * 2)) ^ ((uint)(d & 7) << 4);
        *(uint2*)((char*)Vpre + (((size_t)(kvh * NT + tile)) << 14) + byte) =
            make_uint2(lo, hi);
    }
}

extern "C" __global__ __launch_bounds__(256)
void attn_fwd(const float* __restrict__ Q, const ushort* __restrict__ Kpre,
              const ushort* __restrict__ Vpre, float* __restrict__ O)
{
    // pair heavy with light: CU hosting blocks b and b+256 gets qt=p and 31-p
    const int bid = blockIdx.x;
    const int h   = bid & 15;
    const int p   = bid >> 4;                 // 0..31
    const int qt  = (p < 16) ? p : 47 - p;
    const int kvh = h >> 2;                   // gqa_group_size = 4
    const int q0  = qt * QBLK;
    const int tid  = threadIdx.x;
    const int w    = tid >> 6;
    const int lane = tid & 63;
    const int g    = lane >> 4;   // 0..3
    const int r    = lane & 15;   // 0..15

    // double-buffered swizzled bf16 tile images + per-wave P buffer (72 KB)
    __shared__ ushort Ksh[2][KVBLK * DIM];    // 2 x 16 KB
    __shared__ ushort Vtsh[2][DIM * KVBLK];   // 2 x 16 KB
    __shared__ ushort Psh[4 * 16 * 64];       // 8 KB

    const float qscale = 0.08838834764831845f * 1.4426950408889634f; // 1/sqrt(D)*log2e
    const uint swz = ((uint)(r & 7)) << 4;

    // ---- Q fragments (B-operand of swapped QK^T: col = q = lane&15) ----
    bf16x8_t qf[4];
    {
        const int qrow = q0 + w * 16 + r;
        const float* qp = Q + ((size_t)h * SEQ + qrow) * DIM + g * 8;
#pragma unroll
        for (int kb = 0; kb < 4; ++kb) {
            float4 f0 = *(const float4*)(qp + kb * 32);
            float4 f1 = *(const float4*)(qp + kb * 32 + 4);
            bf16x8_t a;
            a[0] = (short)f2bf(f0.x * qscale); a[1] = (short)f2bf(f0.y * qscale);
            a[2] = (short)f2bf(f0.z * qscale); a[3] = (short)f2bf(f0.w * qscale);
            a[4] = (short)f2bf(f1.x * qscale); a[5] = (short)f2bf(f1.y * qscale);
            a[6] = (short)f2bf(f1.z * qscale); a[7] = (short)f2bf(f1.w * qscale);
            qf[kb] = a;
        }
    }

    f32x4_t o_acc[8];
#pragma unroll
    for (int i = 0; i < 8; ++i) { f32x4_t z = {0.f, 0.f, 0.f, 0.f}; o_acc[i] = z; }
    float m_r = -1e30f, l_r = 0.f;   // per-lane scalar softmax state (q = r)

    const size_t kvbase = (size_t)kvh * NT;
    const int nt = qt + 1;

    auto stage = [&](int b, int t) {
        const char* kg = (const char*)Kpre + ((kvbase + t) << 14) + tid * 16;
        const char* vg = (const char*)Vpre + ((kvbase + t) << 14) + tid * 16;
        char* kl = (char*)&Ksh[b][0] + tid * 16;
        char* vl = (char*)&Vtsh[b][0] + tid * 16;
#pragma unroll
        for (int c = 0; c < 4; ++c) {
            GLOAD_LDS16(kg + c * 4096, kl + c * 4096);
            GLOAD_LDS16(vg + c * 4096, vl + c * 4096);
        }
    };

    char* pbase = (char*)Psh + w * 2048;

    stage(0, 0);
    __syncthreads();           // drains the stage (vmcnt 0)
    int buf = 0;

    for (int t = 0; t < nt; ++t) {
        if (t + 1 < nt) stage(buf ^ 1, t + 1);   // prefetch flies under compute

        const bool diag = (t == nt - 1);

        // ---- swapped QK^T: S^T[kv][q]; lane holds q = r, kv = m*16+g*4+j2 ----
        f32x4_t sacc[4];
#pragma unroll
        for (int m = 0; m < 4; ++m) { f32x4_t z = {0.f, 0.f, 0.f, 0.f}; sacc[m] = z; }
        __builtin_amdgcn_s_setprio(1);
#pragma unroll
        for (int m = 0; m < 4; ++m) {
            if (diag && m > w) {       // fully-masked kv sub-tile: skip MFMAs
#pragma unroll
                for (int j2 = 0; j2 < 4; ++j2) sacc[m][j2] = -1e30f;
            } else {
                const int krow = m * 16 + r;   // A-frag row = kv
#pragma unroll
                for (int kb = 0; kb < 4; ++kb) {
                    uint byte = ((uint)(krow * 256 + (kb * 32 + g * 8) * 2)) ^ swz;
                    bf16x8_t kf = *(bf16x8_t*)((char*)&Ksh[buf][0] + byte);
                    sacc[m] = __builtin_amdgcn_mfma_f32_16x16x32_bf16(kf, qf[kb], sacc[m], 0, 0, 0);
                }
                if (diag && m == w) {  // partial mask on the diagonal sub-tile
#pragma unroll
                    for (int j2 = 0; j2 < 4; ++j2)
                        if (g * 4 + j2 > r) sacc[m][j2] = -1e30f;
                }
            }
        }
        __builtin_amdgcn_s_setprio(0);

        // ---- row max: 15 local + 2 shfl ----
        float pmax = sacc[0][0];
#pragma unroll
        for (int m = 0; m < 4; ++m)
#pragma unroll
            for (int j2 = 0; j2 < 4; ++j2) pmax = fmaxf(pmax, sacc[m][j2]);
        pmax = fmaxf(pmax, __shfl_xor(pmax, 16, 64));
        pmax = fmaxf(pmax, __shfl_xor(pmax, 32, 64));

        // ---- T13 defer-rescale (exp2 domain, THR = 8) ----
        if (!__all(pmax - m_r <= 8.f)) {
            float mnew = fmaxf(m_r, pmax);
            float alpha = __builtin_exp2f(m_r - mnew);
            m_r = mnew;
            l_r *= alpha;
#pragma unroll
            for (int pr = 0; pr < 4; ++pr) {
                float ao = __shfl(alpha, g * 20 + pr, 64);  // lane with r == g*4+pr
#pragma unroll
                for (int nd = 0; nd < 8; ++nd) o_acc[nd][pr] *= ao;
            }
        }

        // ---- P = exp2(S - m), pack, sum ----
        float psum = 0.f;
        uint Wd[4][2];
#pragma unroll
        for (int m = 0; m < 4; ++m) {
            float p0 = __builtin_exp2f(sacc[m][0] - m_r);
            float p1 = __builtin_exp2f(sacc[m][1] - m_r);
            float p2 = __builtin_exp2f(sacc[m][2] - m_r);
            float p3 = __builtin_exp2f(sacc[m][3] - m_r);
            psum += (p0 + p1) + (p2 + p3);
            Wd[m][0] = (uint)f2bf(p0) | ((uint)f2bf(p1) << 16);
            Wd[m][1] = (uint)f2bf(p2) | ((uint)f2bf(p3) << 16);
        }
        psum += __shfl_xor(psum, 16, 64);
        psum += __shfl_xor(psum, 32, 64);
        l_r += psum;

        // ---- P -> LDS (4x b64), row = q = r, col = kv ----
#pragma unroll
        for (int m = 0; m < 4; ++m) {
            uint byte = ((uint)(r * 128 + m * 32 + g * 8)) ^ swz;
            *(uint2*)(pbase + byte) = make_uint2(Wd[m][0], Wd[m][1]);
        }
        asm volatile("s_waitcnt lgkmcnt(0)" ::: "memory");

        // ---- PV: O[q][d] += P[q][kv] V[kv][d] ----
        __builtin_amdgcn_s_setprio(1);
#pragma unroll
        for (int kb = 0; kb < 2; ++kb) {
            uint pbyte = ((uint)(r * 128 + kb * 64 + g * 16)) ^ swz;
            bf16x8_t pa = *(bf16x8_t*)(pbase + pbyte);
#pragma unroll
            for (int nd = 0; nd < 8; ++nd) {
                int d = nd * 16 + r;
                uint vbyte = ((uint)(d * 128 + (kb * 32 + g * 8) * 2)) ^ swz;
                bf16x8_t vb = *(bf16x8_t*)((char*)&Vtsh[buf][0] + vbyte);
                o_acc[nd] = __builtin_amdgcn_mfma_f32_16x16x32_bf16(pa, vb, o_acc[nd], 0, 0, 0);
            }
        }
        __builtin_amdgcn_s_setprio(0);

        __syncthreads();   // drains prefetch, frees buf for next stage
        buf ^= 1;
    }

    // ---- epilogue: O = acc / l (l redistributed from q=r lanes) ----
#pragma unroll
    for (int pr = 0; pr < 4; ++pr) {
        float lq = __shfl(l_r, g * 20 + pr, 64);
        float inv = 1.0f / lq;
        int qrow = q0 + w * 16 + g * 4 + pr;
        float* op = O + ((size_t)h * SEQ + qrow) * DIM;
#pragma unroll
        for (int nd = 0; nd < 8; ++nd)
            op[nd * 16 + r] = o_acc[nd][pr] * inv;
    }
}

extern "C" void kernel_launch(void* const* d_in, const int* in_sizes, int n_in,
                              void* d_out, int out_size, void* d_ws, size_t ws_size,
                              hipStream_t stream) {
    const float* Q = (const float*)d_in[0];
    const float* K = (const float*)d_in[1];
    const float* V = (const float*)d_in[2];
    float* O = (float*)d_out;
    ushort* Kpre = (ushort*)d_ws;                          // 2 MB
    ushort* Vpre = (ushort*)((char*)d_ws + (2u << 20));    // 2 MB
    prep_kv<<<2048, 256, 0, stream>>>(K, V, Kpre, Vpre);
    attn_fwd<<<dim3(512), 256, 0, stream>>>(Q, Kpre, Vpre, O);
}

// Round 8
// 120.927 us; speedup vs baseline: 2.1386x; 1.1650x over previous
//
#include <hip/hip_runtime.h>
#include <hip/hip_bf16.h>

// GQA causal attention fwd: B=1, H=16, HKV=4, S=2048, D=128, fp32 in/out.
// Round 8 (r7 + addrspace fix): 32x32x16 MFMA, swapped QK^T AND swapped PV
// (O^T = V^T P^T) so all softmax state is per-lane (q = lane&31). In-register
// P via cvt_pk + permlane32_swap (T12) — no P LDS round trip. 4 waves =
// (q-half, kv-half); split-kv merge in epilogue. Double-buffered
// global_load_lds staging from pre-converted swizzled bf16 images.

#define NH    16
#define NHKV  4
#define SEQ   2048
#define DIM   128
#define QBLK  64
#define KVBLK 64
#define NT    (SEQ / KVBLK)   // 32 kv tiles

typedef __attribute__((ext_vector_type(8)))  short bf16x8_t;
typedef __attribute__((ext_vector_type(16))) float f32x16_t;

__device__ inline ushort f2bf(float f) {
    uint x = __float_as_uint(f);
    uint r = (x + 0x7fffu + ((x >> 16) & 1u)) >> 16;
    return (ushort)r;
}

__device__ inline uint cvtpk_bf16(float lo, float hi) {
    uint r;
    asm("v_cvt_pk_bf16_f32 %0, %1, %2" : "=v"(r) : "v"(lo), "v"(hi));
    return r;
}

#define GLOAD_LDS16(gsrc, ldst) \
    __builtin_amdgcn_global_load_lds( \
        (const __attribute__((address_space(1))) void*)(gsrc), \
        (__attribute__((address_space(3))) void*)(ldst), 16, 0, 0)

// ---- prep: K -> bf16 swizzled [kvh][tile][kv*256 + d*2 ^ ((kv&7)<<4)],
//            V -> bf16 transposed swizzled [kvh][tile][d*128 + kv*2 ^ ((d&7)<<4)]
extern "C" __global__ __launch_bounds__(256)
void prep_kv(const float* __restrict__ K, const float* __restrict__ V,
             ushort* __restrict__ Kpre, ushort* __restrict__ Vpre)
{
    int gid = blockIdx.x * 256 + threadIdx.x;
    if (blockIdx.x < 1024) {
        int kvh = gid >> 16; int rem = gid & 65535;
        int s = rem >> 5; int dq = (rem & 31) << 2;
        float4 f = *(const float4*)(K + ((size_t)(kvh * SEQ + s)) * DIM + dq);
        uint lo = (uint)f2bf(f.x) | ((uint)f2bf(f.y) << 16);
        uint hi = (uint)f2bf(f.z) | ((uint)f2bf(f.w) << 16);
        int tile = s >> 6, row = s & 63;
        uint byte = ((uint)(row * 256 + dq * 2)) ^ ((uint)(row & 7) << 4);
        *(uint2*)((char*)Kpre + (((size_t)(kvh * NT + tile)) << 14) + byte) =
            make_uint2(lo, hi);
    } else {
        int g2 = gid - 1024 * 256;
        int kvh = g2 >> 16; int rem = g2 & 65535;
        int d = rem & 127; int t2 = rem >> 7;
        int tile = t2 >> 4; int kv = (t2 & 15) << 2;
        const float* b = V + ((size_t)(kvh * SEQ + tile * 64 + kv)) * DIM + d;
        uint lo = (uint)f2bf(b[0])       | ((uint)f2bf(b[DIM]) << 16);
        uint hi = (uint)f2bf(b[2 * DIM]) | ((uint)f2bf(b[3 * DIM]) << 16);
        uint byte = ((uint)(d * 128 + kv * 2)) ^ ((uint)(d & 7) << 4);
        *(uint2*)((char*)Vpre + (((size_t)(kvh * NT + tile)) << 14) + byte) =
            make_uint2(lo, hi);
    }
}

extern "C" __global__ __launch_bounds__(256, 2)
void attn_fwd(const float* __restrict__ Q, const ushort* __restrict__ Kpre,
              const ushort* __restrict__ Vpre, float* __restrict__ O)
{
    // pair heavy with light: CU hosting blocks b and b+256 gets qt=p and 31-p
    const int bid = blockIdx.x;
    const int h   = bid & 15;
    const int p   = bid >> 4;                 // 0..31
    const int qt  = (p < 16) ? p : 47 - p;
    const int kvh = h >> 2;                   // gqa_group_size = 4
    const int q0  = qt * QBLK;
    const int tid  = threadIdx.x;
    const int w    = tid >> 6;
    const int qh   = w >> 1;      // q-half   (0: q[0:32), 1: q[32:64))
    const int kh   = w & 1;       // kv-half  (0: kv[0:32), 1: kv[32:64))
    const int lane = tid & 63;
    const int q31  = lane & 31;
    const int hi   = lane >> 5;

    // layout: [K buf0 16K][K buf1 16K][Vt buf0 16K][Vt buf1 16K]; merge aliases
    __shared__ char smem[65536];
    char* smb = &smem[0];   // runtime-generic pointer (no static initializer)

    const float qscale = 0.08838834764831845f * 1.4426950408889634f; // 1/sqrt(D)*log2e

    // ---- Q fragments: B-frag of swapped QK^T (col = q = lane&31, k = hi*8+i)
    bf16x8_t qf[8];
    const int qrow = q0 + qh * 32 + q31;
    {
        const float* qp = Q + ((size_t)h * SEQ + qrow) * DIM + hi * 8;
#pragma unroll
        for (int ks = 0; ks < 8; ++ks) {
            float4 f0 = *(const float4*)(qp + ks * 16);
            float4 f1 = *(const float4*)(qp + ks * 16 + 4);
            bf16x8_t a;
            a[0] = (short)f2bf(f0.x * qscale); a[1] = (short)f2bf(f0.y * qscale);
            a[2] = (short)f2bf(f0.z * qscale); a[3] = (short)f2bf(f0.w * qscale);
            a[4] = (short)f2bf(f1.x * qscale); a[5] = (short)f2bf(f1.y * qscale);
            a[6] = (short)f2bf(f1.z * qscale); a[7] = (short)f2bf(f1.w * qscale);
            qf[ks] = a;
        }
    }

    // O^T accumulator: 4 d-tiles (d = m*32 + crow), col = q = lane&31
    f32x16_t oacc[4];
#pragma unroll
    for (int m = 0; m < 4; ++m)
#pragma unroll
        for (int i = 0; i < 16; ++i) oacc[m][i] = 0.f;
    float m_r = -1e30f, l_r = 0.f;   // per-lane softmax state for q = lane&31

    const size_t kvbase = (size_t)kvh * NT;
    const int nt = qt + 1;

    auto stage = [&](int b, int t) {
        const char* kg = (const char*)Kpre + ((kvbase + t) << 14) + tid * 16;
        const char* vg = (const char*)Vpre + ((kvbase + t) << 14) + tid * 16;
        char* kl = smb + b * 16384 + tid * 16;
        char* vl = smb + 32768 + b * 16384 + tid * 16;
#pragma unroll
        for (int c = 0; c < 4; ++c) {
            GLOAD_LDS16(kg + c * 4096, kl + c * 4096);
            GLOAD_LDS16(vg + c * 4096, vl + c * 4096);
        }
    };

    stage(0, 0);
    __syncthreads();           // drains the stage (vmcnt 0)
    int buf = 0;

    const int  kvrow = kh * 32 + q31;              // A-frag row of K (kv)
    const uint kswz  = ((uint)(kvrow & 7)) << 4;

    for (int t = 0; t < nt; ++t) {
        if (t + 1 < nt) stage(buf ^ 1, t + 1);     // prefetch flies under compute
        const bool diag = (t == nt - 1);

        if (!(diag && w == 1)) {     // wave (qh=0,kh=1) fully masked on diag
            // ---- swapped QK^T: S^T[kv][q] one 32x32 tile per wave ----
            f32x16_t sacc;
#pragma unroll
            for (int i = 0; i < 16; ++i) sacc[i] = 0.f;
            const char* kb = smb + buf * 16384;
            __builtin_amdgcn_s_setprio(1);
#pragma unroll
            for (int ks = 0; ks < 8; ++ks) {
                uint byte = ((uint)(kvrow * 256 + ks * 32 + hi * 16)) ^ kswz;
                bf16x8_t kf = *(bf16x8_t*)(kb + byte);
                sacc = __builtin_amdgcn_mfma_f32_32x32x16_bf16(kf, qf[ks], sacc, 0, 0, 0);
            }
            __builtin_amdgcn_s_setprio(0);

            // ---- causal mask on the diagonal sub-tile (kh == qh waves) ----
            if (diag && (w == 0 || w == 3)) {
#pragma unroll
                for (int reg = 0; reg < 16; ++reg) {
                    int crow = (reg & 3) + 8 * (reg >> 2) + 4 * hi;   // kv-local
                    if (crow > q31) sacc[reg] = -1e30f;
                }
            }

            // ---- per-lane row max (15 local + 1 pair shfl) ----
            float pmax = sacc[0];
#pragma unroll
            for (int i = 1; i < 16; ++i) pmax = fmaxf(pmax, sacc[i]);
            pmax = fmaxf(pmax, __shfl_xor(pmax, 32, 64));

            // ---- T13 defer-rescale (exp2 domain, THR = 8) ----
            if (!__all(pmax - m_r <= 8.f)) {
                float mnew = fmaxf(m_r, pmax);
                float alpha = __builtin_exp2f(m_r - mnew);
                m_r = mnew;
                l_r *= alpha;
#pragma unroll
                for (int m = 0; m < 4; ++m)
#pragma unroll
                    for (int i = 0; i < 16; ++i) oacc[m][i] *= alpha;
            }

            // ---- P = exp2(S - m) ----
            float pv[16];
            float psum = 0.f;
#pragma unroll
            for (int i = 0; i < 16; ++i) {
                pv[i] = __builtin_exp2f(sacc[i] - m_r);
                psum += pv[i];
            }
            psum += __shfl_xor(psum, 32, 64);
            l_r += psum;

            // ---- T12: in-register P -> PV B-frags via cvt_pk + permlane32_swap
            bf16x8_t pa[2];
#pragma unroll
            for (int hf = 0; hf < 2; ++hf) {
                uint a0 = cvtpk_bf16(pv[hf * 8 + 0], pv[hf * 8 + 1]);
                uint a1 = cvtpk_bf16(pv[hf * 8 + 2], pv[hf * 8 + 3]);
                uint b0 = cvtpk_bf16(pv[hf * 8 + 4], pv[hf * 8 + 5]);
                uint b1 = cvtpk_bf16(pv[hf * 8 + 6], pv[hf * 8 + 7]);
                asm volatile("v_permlane32_swap_b32 %0, %1" : "+v"(a0), "+v"(b0));
                asm volatile("v_permlane32_swap_b32 %0, %1" : "+v"(a1), "+v"(b1));
                uint4 tmp = make_uint4(a0, a1, b0, b1);
                pa[hf] = *(bf16x8_t*)&tmp;
            }

            // ---- swapped PV: O^T[d][q] += V^T[d][kv] P^T[kv][q] ----
            const char* vb = smb + 32768 + buf * 16384;
            __builtin_amdgcn_s_setprio(1);
#pragma unroll
            for (int m = 0; m < 4; ++m) {
                const int drow = m * 32 + q31;
                const uint vswz = ((uint)(drow & 7)) << 4;
#pragma unroll
                for (int ks2 = 0; ks2 < 2; ++ks2) {
                    uint byte = ((uint)(drow * 128 + kh * 64 + ks2 * 32 + hi * 16)) ^ vswz;
                    bf16x8_t vf = *(bf16x8_t*)(vb + byte);
                    oacc[m] = __builtin_amdgcn_mfma_f32_32x32x16_bf16(vf, pa[ks2], oacc[m], 0, 0, 0);
                }
            }
            __builtin_amdgcn_s_setprio(0);
        }

        __syncthreads();   // drains prefetch, frees buf for next stage
        buf ^= 1;
    }

    // ---- split-kv merge (kh=1 -> LDS, kh=0 merges + writes out) ----
    float* fb  = (float*)smb;         // m/l: [qh][2][32]
    float* fb2 = fb + 128;            // O^T: [qh][d=128][q=32] = 32KB
    if (kh == 1) {
        if (hi == 0) { fb[qh * 64 + q31] = m_r; fb[qh * 64 + 32 + q31] = l_r; }
#pragma unroll
        for (int m = 0; m < 4; ++m)
#pragma unroll
            for (int reg = 0; reg < 16; ++reg) {
                int d = m * 32 + (reg & 3) + 8 * (reg >> 2) + 4 * hi;
                fb2[(qh * 128 + d) * 32 + q31] = oacc[m][reg];
            }
    }
    __syncthreads();
    if (kh == 0) {
        float m1 = fb[qh * 64 + q31];
        float l1 = fb[qh * 64 + 32 + q31];
        float mN = fmaxf(m_r, m1);
        float a0 = __builtin_exp2f(m_r - mN);
        float a1 = __builtin_exp2f(m1 - mN);
        float inv = 1.0f / (l_r * a0 + l1 * a1);
        a0 *= inv; a1 *= inv;
        float* op = O + ((size_t)h * SEQ + qrow) * DIM;
#pragma unroll
        for (int m = 0; m < 4; ++m)
#pragma unroll
            for (int rq = 0; rq < 4; ++rq) {
                int d0 = m * 32 + 8 * rq + 4 * hi;
                float4 v;
                v.x = oacc[m][rq * 4 + 0] * a0 + fb2[(qh * 128 + d0 + 0) * 32 + q31] * a1;
                v.y = oacc[m][rq * 4 + 1] * a0 + fb2[(qh * 128 + d0 + 1) * 32 + q31] * a1;
                v.z = oacc[m][rq * 4 + 2] * a0 + fb2[(qh * 128 + d0 + 2) * 32 + q31] * a1;
                v.w = oacc[m][rq * 4 + 3] * a0 + fb2[(qh * 128 + d0 + 3) * 32 + q31] * a1;
                *(float4*)(op + d0) = v;
            }
    }
}

extern "C" void kernel_launch(void* const* d_in, const int* in_sizes, int n_in,
                              void* d_out, int out_size, void* d_ws, size_t ws_size,
                              hipStream_t stream) {
    const float* Q = (const float*)d_in[0];
    const float* K = (const float*)d_in[1];
    const float* V = (const float*)d_in[2];
    float* O = (float*)d_out;
    ushort* Kpre = (ushort*)d_ws;                          // 2 MB
    ushort* Vpre = (ushort*)((char*)d_ws + (2u << 20));    // 2 MB
    prep_kv<<<2048, 256, 0, stream>>>(K, V, Kpre, Vpre);
    attn_fwd<<<dim3(512), 256, 0, stream>>>(Q, Kpre, Vpre, O);
}